// Round 4
// baseline (75.482 us; speedup 1.0000x reference)
//
#include <hip/hip_runtime.h>
#include <hip/hip_bf16.h>

// Problem constants (B,S,H,P) = (512, 256, 768, 32)
#define B_  512
#define S_  256
#define H_  768
#define P_  32
#define K1_ 2304   // 3H
#define K2_ 1536   // 2H
#define N_  768
#define M_  512
#define NK1 72     // K1/32
#define NK2 48     // K2/32
#define CVT_BLOCKS 128

typedef __attribute__((ext_vector_type(8))) short bf16x8v;
typedef __attribute__((ext_vector_type(4))) float f32x4v;

// Fragment layout (bf16), MFMA 16x16x32 operand order:
//   frag[t16][k32][lane][8], lane = kg*16 + r; element (t,k):
//   t = t16*16 + r, k = k32*32 + kg*8 + e.

__device__ inline unsigned short bfb(float x) {
  __hip_bfloat16 h = __float2bfloat16(x);  // RNE
  return *reinterpret_cast<unsigned short*>(&h);
}

__device__ inline void store4_frag(__hip_bfloat16* __restrict__ buf, int NK,
                                   int m, int k, float4 v) {
  int m16 = m >> 4, mr = m & 15, k32 = k >> 5, kg = (k >> 3) & 3, e = k & 7;
  size_t off = ((size_t)(m16 * NK + k32) * 64 + kg * 16 + mr) * 8 + e;
  ushort4 u;
  u.x = bfb(v.x); u.y = bfb(v.y); u.z = bfb(v.z); u.w = bfb(v.w);
  *reinterpret_cast<ushort4*>(buf + off) = u;
}

// ---------------------------------------------------------------------------
// Kernel 1 (fused): blocks [0,2B): (batch,tensor) mean-pool -> A-frag bf16
//                   blocks [2B,2B+CVT_BLOCKS): W1/W2 fp32 -> B-frag bf16
// ---------------------------------------------------------------------------
__global__ __launch_bounds__(192) void pool_cvt_kernel(
    const float* __restrict__ phys, const float* __restrict__ proc,
    const float* __restrict__ micro, const int* __restrict__ pos,
    const float* __restrict__ W1, const float* __restrict__ W2,
    __hip_bfloat16* __restrict__ A1f, __hip_bfloat16* __restrict__ A2f,
    __hip_bfloat16* __restrict__ W1f, __hip_bfloat16* __restrict__ W2f) {
  const int t = threadIdx.x;  // 0..191
  const int NPOOL = 2 * B_;
  if (blockIdx.x < NPOOL) {
    const int b   = blockIdx.x >> 1;
    const int sel = blockIdx.x & 1;  // 0 = proc, 1 = micro
    __shared__ int sp[P_];
    __shared__ int scnt;
    if (t < 64) {  // wave 0 compacts valid positions
      int p = (t < P_) ? pos[b * P_ + t] : -1;
      bool valid = (p != -1);
      unsigned long long m = __ballot(valid);
      int pre = __popcll(m & ((1ull << t) - 1ull));
      if (valid) sp[pre] = p;
      if (t == 0) scnt = (int)__popcll(m);
    }
    __syncthreads();
    const int c = scnt;  // >= 1
    const float inv = 1.0f / (float)c;

    const int H4 = H_ / 4;  // 192
    const float* base = (sel == 0) ? proc : micro;
    const float4* srcb = (const float4*)(base + (size_t)b * S_ * H_);

    // issue sentinel loads early (independent of gather)
    float4 sent = srcb[t];  // row 0
    float4 sph = make_float4(0.f, 0.f, 0.f, 0.f);
    if (sel == 0) sph = ((const float4*)(phys + (size_t)b * S_ * H_))[t];

    float4 s0 = make_float4(0.f, 0.f, 0.f, 0.f);
    float4 s1 = make_float4(0.f, 0.f, 0.f, 0.f);
    int i = 0;
    for (; i + 8 <= c; i += 8) {
      float4 v0 = srcb[(size_t)sp[i+0] * H4 + t];
      float4 v1 = srcb[(size_t)sp[i+1] * H4 + t];
      float4 v2 = srcb[(size_t)sp[i+2] * H4 + t];
      float4 v3 = srcb[(size_t)sp[i+3] * H4 + t];
      float4 v4 = srcb[(size_t)sp[i+4] * H4 + t];
      float4 v5 = srcb[(size_t)sp[i+5] * H4 + t];
      float4 v6 = srcb[(size_t)sp[i+6] * H4 + t];
      float4 v7 = srcb[(size_t)sp[i+7] * H4 + t];
      s0.x += v0.x + v1.x + v2.x + v3.x;  s1.x += v4.x + v5.x + v6.x + v7.x;
      s0.y += v0.y + v1.y + v2.y + v3.y;  s1.y += v4.y + v5.y + v6.y + v7.y;
      s0.z += v0.z + v1.z + v2.z + v3.z;  s1.z += v4.z + v5.z + v6.z + v7.z;
      s0.w += v0.w + v1.w + v2.w + v3.w;  s1.w += v4.w + v5.w + v6.w + v7.w;
    }
    for (; i + 2 <= c; i += 2) {
      float4 v0 = srcb[(size_t)sp[i+0] * H4 + t];
      float4 v1 = srcb[(size_t)sp[i+1] * H4 + t];
      s0.x += v0.x + v1.x; s0.y += v0.y + v1.y;
      s0.z += v0.z + v1.z; s0.w += v0.w + v1.w;
    }
    if (i < c) {
      float4 v = srcb[(size_t)sp[i] * H4 + t];
      s0.x += v.x; s0.y += v.y; s0.z += v.z; s0.w += v.w;
    }
    float4 pooled = make_float4((s0.x + s1.x) * inv, (s0.y + s1.y) * inv,
                                (s0.z + s1.z) * inv, (s0.w + s1.w) * inv);

    const int k = t * 4;
    if (sel == 0) {
      store4_frag(A1f, NK1, b, k,          pooled);
      store4_frag(A1f, NK1, b, k + H_,     sent);
      store4_frag(A1f, NK1, b, k + 2*H_,   sph);
    } else {
      store4_frag(A2f, NK2, b, k,          pooled);
      store4_frag(A2f, NK2, b, k + H_,     sent);
    }
  } else {
    // ---- W conversion: grid-stride over 16B fragment groups ----
    const int NG1 = 48 * NK1 * 64;  // 221184
    const int NG2 = 48 * NK2 * 64;  // 147456
    int tid = (blockIdx.x - NPOOL) * 192 + t;
    const int stride = CVT_BLOCKS * 192;
    for (int g = tid; g < NG1 + NG2; g += stride) {
      const float* W; __hip_bfloat16* Wf; int NK, K, gg;
      if (g < NG1) { W = W1; Wf = W1f; NK = NK1; K = K1_; gg = g; }
      else         { W = W2; Wf = W2f; NK = NK2; K = K2_; gg = g - NG1; }
      int lane = gg & 63;
      int rest = gg >> 6;
      int k32 = rest % NK;
      int n16 = rest / NK;
      int n = n16 * 16 + (lane & 15);
      int k = k32 * 32 + (lane >> 4) * 8;
      const float4* sW = (const float4*)(W + (size_t)n * K + k);
      float4 v0 = sW[0], v1 = sW[1];
      ushort4 u0, u1;
      u0.x = bfb(v0.x); u0.y = bfb(v0.y); u0.z = bfb(v0.z); u0.w = bfb(v0.w);
      u1.x = bfb(v1.x); u1.y = bfb(v1.y); u1.z = bfb(v1.z); u1.w = bfb(v1.w);
      ushort4* d = reinterpret_cast<ushort4*>(Wf + (size_t)gg * 8);
      d[0] = u0; d[1] = u1;
    }
  }
}

// ---------------------------------------------------------------------------
// Kernel 2: fused GEMM + bias + row L2-norm.
// 32 blocks x 768 threads. Block = 32 output rows x full N=768.
// 12 waves, each owning a 32x64 sub-tile (2x4 fragments).
// ---------------------------------------------------------------------------
__device__ inline f32x4v shfl_xor4(f32x4v v, int m) {
  f32x4v r;
  r[0] = __shfl_xor(v[0], m);
  r[1] = __shfl_xor(v[1], m);
  r[2] = __shfl_xor(v[2], m);
  r[3] = __shfl_xor(v[3], m);
  return r;
}

template <int NK>
__device__ inline void gemm_norm_body(const bf16x8v* __restrict__ Af,
                                      const bf16x8v* __restrict__ Wf,
                                      const float* __restrict__ bias,
                                      float* __restrict__ C, int mt) {
  const int tid = threadIdx.x;
  const int w = tid >> 6;        // 0..11
  const int lane = tid & 63;
  const int col = lane & 15;
  const int rg = (lane >> 4) * 4;
  const int n0w = w * 64;

  const bf16x8v* A0 = Af + (size_t)(2 * mt) * NK * 64 + lane;
  const bf16x8v* A1 = A0 + (size_t)NK * 64;
  const bf16x8v* B0 = Wf + (size_t)(4 * w) * NK * 64 + lane;

  f32x4v acc[2][4];
#pragma unroll
  for (int i = 0; i < 2; ++i)
#pragma unroll
    for (int j = 0; j < 4; ++j) acc[i][j] = (f32x4v){0.f, 0.f, 0.f, 0.f};

#pragma unroll 2
  for (int k = 0; k < NK; ++k) {
    bf16x8v a0 = A0[(size_t)k * 64];
    bf16x8v a1 = A1[(size_t)k * 64];
    bf16x8v w0 = B0[(size_t)k * 64];
    bf16x8v w1 = B0[(size_t)k * 64 + (size_t)NK * 64];
    bf16x8v w2 = B0[(size_t)k * 64 + (size_t)2 * NK * 64];
    bf16x8v w3 = B0[(size_t)k * 64 + (size_t)3 * NK * 64];
    acc[0][0] = __builtin_amdgcn_mfma_f32_16x16x32_bf16(a0, w0, acc[0][0], 0, 0, 0);
    acc[0][1] = __builtin_amdgcn_mfma_f32_16x16x32_bf16(a0, w1, acc[0][1], 0, 0, 0);
    acc[0][2] = __builtin_amdgcn_mfma_f32_16x16x32_bf16(a0, w2, acc[0][2], 0, 0, 0);
    acc[0][3] = __builtin_amdgcn_mfma_f32_16x16x32_bf16(a0, w3, acc[0][3], 0, 0, 0);
    acc[1][0] = __builtin_amdgcn_mfma_f32_16x16x32_bf16(a1, w0, acc[1][0], 0, 0, 0);
    acc[1][1] = __builtin_amdgcn_mfma_f32_16x16x32_bf16(a1, w1, acc[1][1], 0, 0, 0);
    acc[1][2] = __builtin_amdgcn_mfma_f32_16x16x32_bf16(a1, w2, acc[1][2], 0, 0, 0);
    acc[1][3] = __builtin_amdgcn_mfma_f32_16x16x32_bf16(a1, w3, acc[1][3], 0, 0, 0);
  }

  // bias add (before norm, as in reference)
#pragma unroll
  for (int j = 0; j < 4; ++j) {
    float bj = bias[n0w + j * 16 + col];
#pragma unroll
    for (int e = 0; e < 4; ++e) { acc[0][j][e] += bj; acc[1][j][e] += bj; }
  }

  // per-row sum of squares: in-lane over j, then butterfly over lane bits 0-3
  f32x4v q0 = (f32x4v){0.f, 0.f, 0.f, 0.f};
  f32x4v q1 = (f32x4v){0.f, 0.f, 0.f, 0.f};
#pragma unroll
  for (int j = 0; j < 4; ++j)
#pragma unroll
    for (int e = 0; e < 4; ++e) {
      q0[e] += acc[0][j][e] * acc[0][j][e];
      q1[e] += acc[1][j][e] * acc[1][j][e];
    }
#pragma unroll
  for (int m = 1; m < 16; m <<= 1) {
    f32x4v t0 = shfl_xor4(q0, m), t1 = shfl_xor4(q1, m);
#pragma unroll
    for (int e = 0; e < 4; ++e) { q0[e] += t0[e]; q1[e] += t1[e]; }
  }

  __shared__ float partials[12][32];
  __shared__ float sinv[32];
  if (col == 0) {
#pragma unroll
    for (int e = 0; e < 4; ++e) {
      partials[w][rg + e]      = q0[e];
      partials[w][16 + rg + e] = q1[e];
    }
  }
  __syncthreads();
  if (tid < 32) {
    float s = 0.f;
#pragma unroll
    for (int ww = 0; ww < 12; ++ww) s += partials[ww][tid];
    sinv[tid] = 1.0f / fmaxf(sqrtf(s), 1e-12f);
  }
  __syncthreads();

  const int m0 = mt * 32;
#pragma unroll
  for (int e = 0; e < 4; ++e) {
    float i0 = sinv[rg + e];
    float i1 = sinv[16 + rg + e];
#pragma unroll
    for (int j = 0; j < 4; ++j) {
      C[(size_t)(m0 + rg + e) * N_ + n0w + j * 16 + col]      = acc[0][j][e] * i0;
      C[(size_t)(m0 + 16 + rg + e) * N_ + n0w + j * 16 + col] = acc[1][j][e] * i1;
    }
  }
}

__global__ __launch_bounds__(768) void gemm_norm_kernel(
    const __hip_bfloat16* __restrict__ A1f, const __hip_bfloat16* __restrict__ A2f,
    const __hip_bfloat16* __restrict__ W1f, const __hip_bfloat16* __restrict__ W2f,
    const float* __restrict__ b1, const float* __restrict__ b2,
    float* __restrict__ out) {
  const int bid = blockIdx.x;
  if (bid < 16) {
    gemm_norm_body<NK1>((const bf16x8v*)A1f, (const bf16x8v*)W1f, b1, out, bid);
  } else {
    gemm_norm_body<NK2>((const bf16x8v*)A2f, (const bf16x8v*)W2f, b2,
                        out + (size_t)M_ * N_, bid - 16);
  }
}

// ---------------------------------------------------------------------------
extern "C" void kernel_launch(void* const* d_in, const int* in_sizes, int n_in,
                              void* d_out, int out_size, void* d_ws, size_t ws_size,
                              hipStream_t stream) {
  const float* phys  = (const float*)d_in[0];
  const float* proc  = (const float*)d_in[1];
  const float* micro = (const float*)d_in[2];
  const int*   pos   = (const int*)d_in[3];
  const float* W1    = (const float*)d_in[4];
  const float* b1    = (const float*)d_in[5];
  const float* W2    = (const float*)d_in[6];
  const float* b2    = (const float*)d_in[7];
  float* out = (float*)d_out;

  // ws layout (bf16): A1f | A2f | W1f | W2f  (~9.4 MB total)
  __hip_bfloat16* A1f = (__hip_bfloat16*)d_ws;
  __hip_bfloat16* A2f = A1f + (size_t)32 * NK1 * 512;
  __hip_bfloat16* W1f = A2f + (size_t)32 * NK2 * 512;
  __hip_bfloat16* W2f = W1f + (size_t)48 * NK1 * 512;

  pool_cvt_kernel<<<2 * B_ + CVT_BLOCKS, 192, 0, stream>>>(
      phys, proc, micro, pos, W1, W2, A1f, A2f, W1f, W2f);
  gemm_norm_kernel<<<32, 768, 0, stream>>>(A1f, A2f, W1f, W2f, b1, b2, out);
}